// Round 6
// baseline (210.588 us; speedup 1.0000x reference)
//
#include <hip/hip_runtime.h>
#include <stdint.h>

typedef unsigned short u16;
typedef unsigned int   u32;
typedef __attribute__((ext_vector_type(8))) short short8;
typedef __attribute__((ext_vector_type(4))) float f32x4;

#define NTOK 4096
#define LOG2E 1.44269504088896340736f
#define QS    (0.125f * LOG2E)

// round-to-nearest-even f32 -> bf16
__device__ __forceinline__ u16 f2bf(float f) {
    u32 u = __builtin_bit_cast(u32, f);
    u += 0x7fffu + ((u >> 16) & 1u);
    return (u16)(u >> 16);
}
__device__ __forceinline__ float bf2f(u16 v) {
    return __builtin_bit_cast(float, (u32)v << 16);
}
// pack two positive floats to bf16 pair (round-half-up), low half = a. 3 VALU ops.
__device__ __forceinline__ u32 pk_hu(float a, float b) {
    u32 ua = __builtin_bit_cast(u32, a) + 0x8000u;
    u32 ub = __builtin_bit_cast(u32, b) + 0x8000u;
    return __builtin_amdgcn_perm(ub, ua, 0x07060302);  // {ub.hi16, ua.hi16}
}

#define MFMA16x32 __builtin_amdgcn_mfma_f32_16x16x32_bf16

// ---------------- kernel 0: one-time weight convert to bf16 ----------------
// wbuf: [mat][d][c] bf16, mat: 0=wq*QS, 1=wk, 2=wv, 3=wm.
__global__ __launch_bounds__(256) void wconv(
    const float* __restrict__ wq, const float* __restrict__ wk,
    const float* __restrict__ wv, const float* __restrict__ wm,
    u16* __restrict__ wbuf)
{
    const int mat = blockIdx.x >> 2;
    const int i   = (blockIdx.x & 3) * 1024 + threadIdx.x * 4;
    const float* src = (mat == 0) ? wq : (mat == 1) ? wk : (mat == 2) ? wv : wm;
    const float sc = (mat == 0) ? QS : 1.0f;
    const float4 v = *(const float4*)(src + i);
    uint2 pk;
    pk.x = (u32)f2bf(v.x * sc) | ((u32)f2bf(v.y * sc) << 16);
    pk.y = (u32)f2bf(v.z * sc) | ((u32)f2bf(v.w * sc) << 16);
    *(uint2*)(wbuf + mat * 4096 + i) = pk;
}

// ---------------- kernel 1: QKV projection via MFMA ----------------
// grid 512 = slab(64 tok) x b(8 low bits -> XCD affinity); block 256 = 4 waves.
// V exits through an LDS transpose (reusing the X tile) -> coalesced b64 stores.
__global__ __launch_bounds__(256) void qkv_mfma3(
    const float* __restrict__ x, const u16* __restrict__ wbuf,
    const float* __restrict__ bq, const float* __restrict__ bk, const float* __restrict__ bv,
    u16* __restrict__ Q, u16* __restrict__ K, u16* __restrict__ Vt)
{
    __shared__ __align__(16) u16 Xl[64 * 64];   // [tok][ch] bf16, 128-B rows, 16B-slot XOR swizzle
    const int tid = threadIdx.x;
    const int b   = blockIdx.x & 7;
    const int n0  = (blockIdx.x >> 3) << 6;
    const int c   = tid & 63;
    const int grp = tid >> 6;

    // stage x: thread reads 4 float4 (16 tokens) of channel-row c
    const float4* xr = (const float4*)(x + ((size_t)(b * 64 + c)) * NTOK + n0);
    float4 xv[4];
#pragma unroll
    for (int k = 0; k < 4; ++k) xv[k] = xr[grp * 4 + k];
#pragma unroll
    for (int k = 0; k < 4; ++k) {
        const float vv[4] = {xv[k].x, xv[k].y, xv[k].z, xv[k].w};
#pragma unroll
        for (int e = 0; e < 4; ++e) {
            const int tok = (grp * 4 + k) * 4 + e;
            Xl[tok * 64 + (((c >> 3) ^ (tok & 7)) * 8) + (c & 7)] = f2bf(vv[e]);
        }
    }
    __syncthreads();

    const int wave = grp;
    const int lane = tid & 63;
    const int quad = lane >> 4;
    const int l15  = lane & 15;
    const int row0 = wave * 16 + l15;           // token within slab

    short8 xf[2];
#pragma unroll
    for (int kk = 0; kk < 2; ++kk)
        xf[kk] = *(const short8*)&Xl[row0 * 64 + (((kk * 4 + quad) ^ (row0 & 7)) * 8)];

    const size_t tokbase = (size_t)b * NTOK + n0 + wave * 16;

    // ---- Q and K (global uint2 stores) ----
#pragma unroll
    for (int mat = 0; mat < 2; ++mat) {
        const float* bias = (mat == 0) ? bq : bk;
        const float bsc = (mat == 0) ? QS : 1.0f;
#pragma unroll
        for (int mt = 0; mt < 4; ++mt) {
            short8 wf0 = *(const short8*)(wbuf + mat * 4096 + (mt * 16 + l15) * 64 + quad * 8);
            short8 wf1 = *(const short8*)(wbuf + mat * 4096 + (mt * 16 + l15) * 64 + 32 + quad * 8);
            f32x4 acc = {0.f, 0.f, 0.f, 0.f};
            acc = MFMA16x32(wf0, xf[0], acc, 0, 0, 0);
            acc = MFMA16x32(wf1, xf[1], acc, 0, 0, 0);
            const float4 b4 = *(const float4*)(bias + mt * 16 + quad * 4);
            uint2 pk;
            pk.x = (u32)f2bf(acc[0] + b4.x * bsc) | ((u32)f2bf(acc[1] + b4.y * bsc) << 16);
            pk.y = (u32)f2bf(acc[2] + b4.z * bsc) | ((u32)f2bf(acc[3] + b4.w * bsc) << 16);
            u16* dst = (mat == 0) ? Q : K;
            *(uint2*)(dst + (tokbase + l15) * 64 + mt * 16 + quad * 4) = pk;
        }
    }

    // ---- V: compute, stage to LDS (transposed, swizzled), coalesced store ----
    __syncthreads();                  // all xf reads done; Xl region reusable as Vl
    u16* Vl = Xl;                     // [d 0..63][tok 0..63] bf16, swizzled 16B slots
    const int tok = wave * 16 + l15;
#pragma unroll
    for (int mt = 0; mt < 4; ++mt) {
        short8 wf0 = *(const short8*)(wbuf + 2 * 4096 + (mt * 16 + l15) * 64 + quad * 8);
        short8 wf1 = *(const short8*)(wbuf + 2 * 4096 + (mt * 16 + l15) * 64 + 32 + quad * 8);
        f32x4 acc = {0.f, 0.f, 0.f, 0.f};
        acc = MFMA16x32(wf0, xf[0], acc, 0, 0, 0);
        acc = MFMA16x32(wf1, xf[1], acc, 0, 0, 0);
        const float4 b4 = *(const float4*)(bv + mt * 16 + quad * 4);
        const float o[4] = {acc[0] + b4.x, acc[1] + b4.y, acc[2] + b4.z, acc[3] + b4.w};
#pragma unroll
        for (int r = 0; r < 4; ++r) {
            const int d = mt * 16 + quad * 4 + r;
            Vl[d * 64 + ((((tok >> 3) ^ ((d >> 1) & 7)) & 7) * 8) + (tok & 7)] = f2bf(o[r]);
        }
    }
    __syncthreads();

    u16* Vo = Vt + (size_t)b * 64 * NTOK;
#pragma unroll
    for (int dd = 0; dd < 4; ++dd) {
        const int d2   = (tid >> 4) + dd * 16;
        const int tok0 = (tid & 15) * 4;
        const int slot = ((tok0 >> 3) ^ ((d2 >> 1) & 7)) & 7;
        const uint2 v2 = *(const uint2*)(Vl + d2 * 64 + slot * 8 + (tok0 & 7));
        *(uint2*)(Vo + (size_t)d2 * NTOK + n0 + tok0) = v2;
    }
}

// ---------------- kernel 2: fused attention + mix + 2x2 pool ----------------
// grid 256 = oh(32) x b(8 low bits). Block 1024 = 16 waves = 4 Q-groups (h) x
// 4 KV-slices (s). Wave: 32 Q-rows, 1024-token slice, O = 32 AGPR, lp via
// ones-MFMA. P transit: per-wave 4 KB, 128-B rows, b64 writes at wp=tg^l15
// (conflict-free), b128 reads at quad^(l15>>1) + odd-lane half-swap.
// RACE FIX (R5->R6): epilogue lp/section writes target OTHER waves' P regions
// -> must barrier after the K-loop before any epilogue LDS write. Also barrier
// between section reads and the M0 overwrite of the same region.
__global__ __launch_bounds__(1024, 4) void attn5(
    const u16* __restrict__ Q, const u16* __restrict__ K,
    const u16* __restrict__ Vt, const u16* __restrict__ wbuf,
    const float* __restrict__ bm, float* __restrict__ out)
{
    __shared__ __align__(16) char smem[65536];
    const int tid  = threadIdx.x;
    const int wave = tid >> 6;
    const int lane = tid & 63;
    const int quad = lane >> 4;
    const int l15  = lane & 15;
    const int h    = wave >> 2;          // Q group (32 rows)
    const int s    = wave & 3;           // KV slice (1024 tokens)
    const int b    = blockIdx.x & 7;
    const int oh   = blockIdx.x >> 3;
    const int n0   = oh * 128;

    // Q B-frags for my 32 rows
    const u16* qbase = Q + ((size_t)(b * NTOK + n0 + h * 32 + l15)) * 64 + quad * 8;
    short8 qf[2][2];
#pragma unroll
    for (int nt2 = 0; nt2 < 2; ++nt2)
#pragma unroll
        for (int kk = 0; kk < 2; ++kk)
            qf[nt2][kk] = *(const short8*)(qbase + nt2 * 1024 + kk * 32);

    const u16* Kb = K + ((size_t)b * NTOK + s * 1024) * 64;
    const u16* Vb = Vt + (size_t)b * 64 * NTOK + s * 1024;
    u16* Pw = (u16*)(smem + wave * 4096);    // P[32 rows][16 wp-slots x 8B]

    short8 onesB;
#pragma unroll
    for (int j = 0; j < 8; ++j) onesB[j] = (short)0x3F80;  // bf16 1.0

    f32x4 O[2][4];
#pragma unroll
    for (int nt2 = 0; nt2 < 2; ++nt2)
#pragma unroll
        for (int ct = 0; ct < 4; ++ct) O[nt2][ct] = (f32x4){0.f, 0.f, 0.f, 0.f};
    f32x4 lpa[2] = {{0.f,0.f,0.f,0.f},{0.f,0.f,0.f,0.f}};

#pragma unroll 1
    for (int t = 0; t < 32; ++t) {           // 32 tiles x 32 tokens = 1024
        const u16* kt = Kb + (size_t)t * 2048;
        short8 kf[2][2];
#pragma unroll
        for (int mtk = 0; mtk < 2; ++mtk)
#pragma unroll
            for (int kk = 0; kk < 2; ++kk)
                kf[mtk][kk] = *(const short8*)(kt + (mtk * 16 + l15) * 64 + kk * 32 + quad * 8);
        short8 vf[4];
#pragma unroll
        for (int ct = 0; ct < 4; ++ct)
            vf[ct] = *(const short8*)(Vb + (size_t)(ct * 16 + l15) * NTOK + t * 32 + quad * 8);

        // S^T = K.Q^T -> exp2 -> P (b64, conflict-free swizzle)
#pragma unroll
        for (int mtk = 0; mtk < 2; ++mtk) {
#pragma unroll
            for (int nt2 = 0; nt2 < 2; ++nt2) {
                f32x4 sv = {0.f, 0.f, 0.f, 0.f};
                sv = MFMA16x32(kf[mtk][0], qf[nt2][0], sv, 0, 0, 0);
                sv = MFMA16x32(kf[mtk][1], qf[nt2][1], sv, 0, 0, 0);
                const float p0 = __builtin_amdgcn_exp2f(sv[0]);
                const float p1 = __builtin_amdgcn_exp2f(sv[1]);
                const float p2 = __builtin_amdgcn_exp2f(sv[2]);
                const float p3 = __builtin_amdgcn_exp2f(sv[3]);
                uint2 pk;
                pk.x = pk_hu(p0, p1);
                pk.y = pk_hu(p2, p3);
                const int row = nt2 * 16 + l15;
                const int wp  = (mtk * 4 + quad) ^ l15;
                *(uint2*)(Pw + row * 64 + wp * 4) = pk;
            }
        }
        // P A-frags -> lp (ones-MFMA) + PV
#pragma unroll
        for (int nt2 = 0; nt2 < 2; ++nt2) {
            const int lrow = nt2 * 16 + l15;
            const uint4 rw = *(const uint4*)(Pw + lrow * 64 + (quad ^ (l15 >> 1)) * 8);
            uint4 pu;
            pu.x = (l15 & 1) ? rw.z : rw.x;
            pu.y = (l15 & 1) ? rw.w : rw.y;
            pu.z = (l15 & 1) ? rw.x : rw.z;
            pu.w = (l15 & 1) ? rw.y : rw.w;
            const short8 pf = __builtin_bit_cast(short8, pu);
            lpa[nt2] = MFMA16x32(pf, onesB, lpa[nt2], 0, 0, 0);
#pragma unroll
            for (int ct = 0; ct < 4; ++ct)
                O[nt2][ct] = MFMA16x32(pf, vf[ct], O[nt2][ct], 0, 0, 0);
        }
    }

    __syncthreads();   // RACE FIX: all waves' P traffic drained before epilogue writes

    // ---- epilogue: partial exchange (no LDS atomics) ----
    // lp partials: wave w -> [52224 + w*128), 32 f32
    if (l15 == 0) {
        float* lpw = (float*)(smem + 52224 + wave * 128);
#pragma unroll
        for (int nt2 = 0; nt2 < 2; ++nt2)
            *(f32x4*)(lpw + nt2 * 16 + quad * 4) = lpa[nt2];
    }
    // O sections (bf16, stride 68 u16) from s != 0 waves: slot idx = h*3 + s-1
    if (s != 0) {
        u16* sec = (u16*)(smem + (h * 3 + s - 1) * 4352);
#pragma unroll
        for (int nt2 = 0; nt2 < 2; ++nt2)
#pragma unroll
            for (int ct = 0; ct < 4; ++ct)
#pragma unroll
                for (int r = 0; r < 4; ++r)
                    sec[(nt2 * 16 + quad * 4 + r) * 68 + ct * 16 + l15] = f2bf(O[nt2][ct][r]);
    }
    __syncthreads();

    float rinv[2][4];
    if (s == 0) {
#pragma unroll
        for (int nt2 = 0; nt2 < 2; ++nt2)
#pragma unroll
            for (int r = 0; r < 4; ++r) {
                const int row = nt2 * 16 + quad * 4 + r;
                float sum = 0.f;
#pragma unroll
                for (int sx = 0; sx < 4; ++sx)
                    sum += ((const float*)(smem + 52224 + (h * 4 + sx) * 128))[row];
                rinv[nt2][r] = 1.0f / sum;
            }
#pragma unroll
        for (int sx = 1; sx < 4; ++sx) {
            const u16* sec = (const u16*)(smem + (h * 3 + sx - 1) * 4352);
#pragma unroll
            for (int nt2 = 0; nt2 < 2; ++nt2)
#pragma unroll
                for (int ct = 0; ct < 4; ++ct)
#pragma unroll
                    for (int r = 0; r < 4; ++r)
                        O[nt2][ct][r] += bf2f(sec[(nt2 * 16 + quad * 4 + r) * 68 + ct * 16 + l15]);
        }
    }
    __syncthreads();   // RACE FIX: section reads complete before M0 overwrites the region

    if (s == 0) {
        // normalize -> M0 bf16 (swizzled) at h*13056
        u16* M0 = (u16*)(smem + h * 13056);
#pragma unroll
        for (int nt2 = 0; nt2 < 2; ++nt2)
#pragma unroll
            for (int ct = 0; ct < 4; ++ct)
#pragma unroll
                for (int r = 0; r < 4; ++r) {
                    const int lr = nt2 * 16 + quad * 4 + r;
                    const int ch = ct * 16 + l15;
                    const float v = O[nt2][ct][r] * rinv[nt2][r];
                    M0[lr * 64 + ((((ch >> 3) ^ (lr & 7)) & 7) * 8) + (ch & 7)] = f2bf(v);
                }
    }
    // all waves: prefetch wm frags + bias while reducers work
    const int rt = wave & 7;             // row-tile for mix
    const int cH = wave >> 3;            // ch half
    short8 wB[2][2];
    float bb[2];
#pragma unroll
    for (int nt2 = 0; nt2 < 2; ++nt2) {
        const int d = cH * 32 + nt2 * 16 + l15;
        wB[nt2][0] = *(const short8*)(wbuf + 3 * 4096 + d * 64 + quad * 8);
        wB[nt2][1] = *(const short8*)(wbuf + 3 * 4096 + d * 64 + 32 + quad * 8);
        bb[nt2] = bm[d];
    }
    __syncthreads();

    // mix: wave (rt, cH): rows rt*16+[0,16), channels cH*32+[0,32)
    const int lr = (rt & 1) * 16 + l15;
    const u16* M0r = (const u16*)(smem + (rt >> 1) * 13056);
    short8 af0 = *(const short8*)(M0r + lr * 64 + ((((0 + quad) ^ (lr & 7)) & 7) * 8));
    short8 af1 = *(const short8*)(M0r + lr * 64 + ((((4 + quad) ^ (lr & 7)) & 7) * 8));
    __syncthreads();                     // all M0 reads done; Mf may alias

    float* Mf = (float*)smem;            // [128][68] f32 = 34816 B
#pragma unroll
    for (int nt2 = 0; nt2 < 2; ++nt2) {
        f32x4 acc = {0.f, 0.f, 0.f, 0.f};
        acc = MFMA16x32(af0, wB[nt2][0], acc, 0, 0, 0);
        acc = MFMA16x32(af1, wB[nt2][1], acc, 0, 0, 0);
#pragma unroll
        for (int r = 0; r < 4; ++r) {
            float v = acc[r] + bb[nt2];
            v = v > 0.f ? v : 0.f;
            Mf[(rt * 16 + quad * 4 + r) * 68 + cH * 32 + nt2 * 16 + l15] = v;
        }
    }
    __syncthreads();

    // 2x2 avg pool (== bilinear 2x downsample, half-pixel)
    const int ow = tid & 31;
    const int cc = (tid >> 5) & 31;
#pragma unroll
    for (int i = 0; i < 2; ++i) {
        const int c = cc + i * 32;
        const float v = 0.25f * (Mf[(2 * ow) * 68 + c] + Mf[(2 * ow + 1) * 68 + c]
                               + Mf[(64 + 2 * ow) * 68 + c] + Mf[(65 + 2 * ow) * 68 + c]);
        out[((size_t)(b * 64 + c) * 32 + oh) * 32 + ow] = v;
    }
}

extern "C" void kernel_launch(void* const* d_in, const int* in_sizes, int n_in,
                              void* d_out, int out_size, void* d_ws, size_t ws_size,
                              hipStream_t stream) {
    (void)in_sizes; (void)n_in; (void)out_size; (void)ws_size;
    const float* x  = (const float*)d_in[0];
    const float* wq = (const float*)d_in[1];
    const float* bq = (const float*)d_in[2];
    const float* wk = (const float*)d_in[3];
    const float* bk = (const float*)d_in[4];
    const float* wv = (const float*)d_in[5];
    const float* bv = (const float*)d_in[6];
    const float* wm = (const float*)d_in[7];
    const float* bm = (const float*)d_in[8];

    // ws: Q bf16 [8][4096][64] | K | Vt [8][64][4096] | wbuf [4][64][64] = 12 MB + 32 KB
    u16* Q    = (u16*)d_ws;
    u16* K    = Q + (size_t)8 * NTOK * 64;
    u16* Vt   = K + (size_t)8 * NTOK * 64;
    u16* wbuf = Vt + (size_t)8 * NTOK * 64;

    wconv<<<16, 256, 0, stream>>>(wq, wk, wv, wm, wbuf);
    qkv_mfma3<<<512, 256, 0, stream>>>(x, wbuf, bq, bk, bv, Q, K, Vt);
    attn5<<<256, 1024, 0, stream>>>(Q, K, Vt, wbuf, bm, (float*)d_out);
}

// Round 7
// 136.708 us; speedup vs baseline: 1.5404x; 1.5404x over previous
//
#include <hip/hip_runtime.h>
#include <stdint.h>

typedef unsigned short u16;
typedef unsigned int   u32;
typedef __attribute__((ext_vector_type(8))) short short8;
typedef __attribute__((ext_vector_type(4))) float f32x4;

#define NTOK 4096
#define LOG2E 1.44269504088896340736f
#define QS    (0.125f * LOG2E)

// round-to-nearest-even f32 -> bf16
__device__ __forceinline__ u16 f2bf(float f) {
    u32 u = __builtin_bit_cast(u32, f);
    u += 0x7fffu + ((u >> 16) & 1u);
    return (u16)(u >> 16);
}
__device__ __forceinline__ float bf2f(u16 v) {
    return __builtin_bit_cast(float, (u32)v << 16);
}
// pack two positive floats to bf16 pair (round-half-up), low half = a. 3 VALU ops.
__device__ __forceinline__ u32 pk_hu(float a, float b) {
    u32 ua = __builtin_bit_cast(u32, a) + 0x8000u;
    u32 ub = __builtin_bit_cast(u32, b) + 0x8000u;
    return __builtin_amdgcn_perm(ub, ua, 0x07060302);  // {ub.hi16, ua.hi16}
}

#define MFMA16x32 __builtin_amdgcn_mfma_f32_16x16x32_bf16

// ---------------- kernel 1: QKV projection via MFMA (wconv folded in) ----------------
// grid 512 = slab(64 tok) x b(8 low bits -> XCD affinity); block 256 = 4 waves.
// Weights converted to bf16 into LDS (stride 72 u16: conflict-free frag reads).
// x staged with DENSE loads (16 lanes cover one 256B channel row).
// Q/K out row-major bf16; V out tile-packed Vp[b][tile(32tok)][ch 64][tok 32].
__global__ __launch_bounds__(256) void qkv_mfma4(
    const float* __restrict__ x,
    const float* __restrict__ wq, const float* __restrict__ bq,
    const float* __restrict__ wk, const float* __restrict__ bk,
    const float* __restrict__ wv, const float* __restrict__ bv,
    u16* __restrict__ Q, u16* __restrict__ K, u16* __restrict__ Vp)
{
    __shared__ __align__(16) u16 Wl[3 * 64 * 72];   // 27648 B, row stride 72 u16
    __shared__ __align__(16) u16 Xl[64 * 64];       // [tok][ch] bf16, swizzled 16B slots
    const int tid  = threadIdx.x;
    const int b    = blockIdx.x & 7;
    const int slab = blockIdx.x >> 3;
    const int n0   = slab << 6;
    const int wave = tid >> 6;
    const int lane = tid & 63;
    const int quad = lane >> 4;
    const int l15  = lane & 15;

    // ---- stage weights (bf16, wq pre-scaled by QS) ----
#pragma unroll
    for (int j = 0; j < 12; ++j) {
        const float* src = (j < 4) ? wq : (j < 8) ? wk : wv;
        const float sc = (j < 4) ? QS : 1.0f;
        const int idx = (j & 3) * 1024 + tid * 4;
        const float4 v = *(const float4*)(src + idx);
        uint2 pk;
        pk.x = (u32)f2bf(v.x * sc) | ((u32)f2bf(v.y * sc) << 16);
        pk.y = (u32)f2bf(v.z * sc) | ((u32)f2bf(v.w * sc) << 16);
        *(uint2*)&Wl[(j >> 2) * 4608 + (idx >> 6) * 72 + (idx & 63)] = pk;
    }

    // ---- stage x: instr g reads 4 full 256B channel rows (dense) ----
    float4 xs[4];
#pragma unroll
    for (int g = 0; g < 4; ++g) {
        const int ch = g * 16 + wave * 4 + quad;
        xs[g] = *(const float4*)(x + ((size_t)(b * 64 + ch)) * NTOK + n0 + l15 * 4);
    }
#pragma unroll
    for (int g = 0; g < 4; ++g) {
        const int ch = g * 16 + wave * 4 + quad;
        const float vv[4] = {xs[g].x, xs[g].y, xs[g].z, xs[g].w};
#pragma unroll
        for (int e = 0; e < 4; ++e) {
            const int tok = l15 * 4 + e;
            Xl[tok * 64 + (((ch >> 3) ^ (tok & 7)) & 7) * 8 + (ch & 7)] = f2bf(vv[e]);
        }
    }
    __syncthreads();

    const int row0 = wave * 16 + l15;           // token within slab
    short8 xf[2];
#pragma unroll
    for (int kk = 0; kk < 2; ++kk)
        xf[kk] = *(const short8*)&Xl[row0 * 64 + (((kk * 4 + quad) ^ (row0 & 7)) & 7) * 8];

    const size_t tokbase = (size_t)b * NTOK + n0 + wave * 16;

    // ---- Q and K ----
#pragma unroll
    for (int mat = 0; mat < 2; ++mat) {
        const float* bias = (mat == 0) ? bq : bk;
        const float bsc = (mat == 0) ? QS : 1.0f;
#pragma unroll
        for (int mt = 0; mt < 4; ++mt) {
            const u16* wr = &Wl[mat * 4608 + (mt * 16 + l15) * 72 + quad * 8];
            const short8 wf0 = *(const short8*)(wr);
            const short8 wf1 = *(const short8*)(wr + 32);
            f32x4 acc = {0.f, 0.f, 0.f, 0.f};
            acc = MFMA16x32(wf0, xf[0], acc, 0, 0, 0);
            acc = MFMA16x32(wf1, xf[1], acc, 0, 0, 0);
            const float4 b4 = *(const float4*)(bias + mt * 16 + quad * 4);
            uint2 pk;
            pk.x = (u32)f2bf(acc[0] + b4.x * bsc) | ((u32)f2bf(acc[1] + b4.y * bsc) << 16);
            pk.y = (u32)f2bf(acc[2] + b4.z * bsc) | ((u32)f2bf(acc[3] + b4.w * bsc) << 16);
            u16* dst = (mat == 0) ? Q : K;
            *(uint2*)(dst + (tokbase + l15) * 64 + mt * 16 + quad * 4) = pk;
        }
    }

    // ---- V: compute, LDS transpose (reuse Xl), tile-packed coalesced store ----
    __syncthreads();
    u16* Vl = Xl;                     // [d][tok] bf16, swizzled 16B slots
    const int tok = wave * 16 + l15;
#pragma unroll
    for (int mt = 0; mt < 4; ++mt) {
        const u16* wr = &Wl[2 * 4608 + (mt * 16 + l15) * 72 + quad * 8];
        const short8 wf0 = *(const short8*)(wr);
        const short8 wf1 = *(const short8*)(wr + 32);
        f32x4 acc = {0.f, 0.f, 0.f, 0.f};
        acc = MFMA16x32(wf0, xf[0], acc, 0, 0, 0);
        acc = MFMA16x32(wf1, xf[1], acc, 0, 0, 0);
        const float4 b4 = *(const float4*)(bv + mt * 16 + quad * 4);
        const float o[4] = {acc[0] + b4.x, acc[1] + b4.y, acc[2] + b4.z, acc[3] + b4.w};
#pragma unroll
        for (int r = 0; r < 4; ++r) {
            const int d = mt * 16 + quad * 4 + r;
            Vl[d * 64 + (((tok >> 3) ^ ((d >> 1) & 7)) & 7) * 8 + (tok & 7)] = f2bf(o[r]);
        }
    }
    __syncthreads();

#pragma unroll
    for (int dd = 0; dd < 4; ++dd) {
        const int d2   = (tid >> 4) + dd * 16;
        const int tok0 = (tid & 15) * 4;
        const int slot = ((tok0 >> 3) ^ ((d2 >> 1) & 7)) & 7;
        const uint2 v2 = *(const uint2*)&Vl[d2 * 64 + slot * 8 + (tok0 & 7)];
        const int gt = slab * 2 + (tok0 >> 5);
        *(uint2*)(Vp + (((size_t)b * 128 + gt) * 64 + d2) * 32 + (tok0 & 31)) = v2;
    }
}

// ---------------- kernel 2: fused attention + mix + 2x2 pool ----------------
// grid 256 = oh(32) x b(8 low bits). Block 512 = 8 waves = 2 Q-halves (h) x
// 4 KV-slices (s). Wave: 64 Q-rows (qf 32 VGPR), 1024-token slice, O 64 AGPR,
// lp via ones-MFMA (16 AGPR). 1-tile software prefetch of kf/vf (R4-proven).
// P transit per wave 4 KB (64 rows x 64B): write uint2 at wp=(mtk*4+quad)^(l15&6),
// read b128 at slot=quad^((l15>>1)&3) -- both conflict-free, NO half-swap.
// V loads from tile-packed Vp: 1KB contiguous, dense L2 lines.
__global__ __launch_bounds__(512, 2) void attn6(
    const u16* __restrict__ Q, const u16* __restrict__ K,
    const u16* __restrict__ Vp,
    const float* __restrict__ wm, const float* __restrict__ bm,
    float* __restrict__ out)
{
    __shared__ __align__(16) char smem[54272];
    const int tid  = threadIdx.x;
    const int wave = tid >> 6;
    const int lane = tid & 63;
    const int quad = lane >> 4;
    const int l15  = lane & 15;
    const int h    = wave >> 2;          // Q half (64 rows)
    const int s    = wave & 3;           // KV slice (1024 tokens)
    const int b    = blockIdx.x & 7;
    const int oh   = blockIdx.x >> 3;
    const int n0   = oh * 128;

    // Q B-frags for my half's 64 rows
    const u16* qbase = Q + ((size_t)(b * NTOK + n0 + h * 64 + l15)) * 64 + quad * 8;
    short8 qf[4][2];
#pragma unroll
    for (int nt = 0; nt < 4; ++nt)
#pragma unroll
        for (int kk = 0; kk < 2; ++kk)
            qf[nt][kk] = *(const short8*)(qbase + nt * 1024 + kk * 32);

    const u16* Kb  = K + ((size_t)b * NTOK + s * 1024) * 64;
    const u16* Vbp = Vp + ((size_t)b * 128 + s * 32) * 2048;   // 64ch*32tok=2048 per tile
    u16* Pw = (u16*)(smem + wave * 4096);    // P[64 rows][8 wp-slots x 8B]

    short8 onesB;
#pragma unroll
    for (int j = 0; j < 8; ++j) onesB[j] = (short)0x3F80;  // bf16 1.0

    f32x4 O[4][4];
#pragma unroll
    for (int nt = 0; nt < 4; ++nt)
#pragma unroll
        for (int ct = 0; ct < 4; ++ct) O[nt][ct] = (f32x4){0.f, 0.f, 0.f, 0.f};
    f32x4 lpa[4] = {{0.f,0.f,0.f,0.f},{0.f,0.f,0.f,0.f},{0.f,0.f,0.f,0.f},{0.f,0.f,0.f,0.f}};

    short8 kf[2][2], vf[4], kf_n[2][2], vf_n[4];
#pragma unroll
    for (int mtk = 0; mtk < 2; ++mtk)
#pragma unroll
        for (int kk = 0; kk < 2; ++kk)
            kf[mtk][kk] = *(const short8*)(Kb + (mtk * 16 + l15) * 64 + kk * 32 + quad * 8);
#pragma unroll
    for (int ct = 0; ct < 4; ++ct)
        vf[ct] = *(const short8*)(Vbp + (ct * 16 + l15) * 32 + quad * 8);

#pragma unroll 1
    for (int t = 0; t < 32; ++t) {           // 32 tiles x 32 tokens = 1024
        // ---- S^T = K.Q^T -> exp2 -> P ----
#pragma unroll
        for (int mtk = 0; mtk < 2; ++mtk) {
#pragma unroll
            for (int nt = 0; nt < 4; ++nt) {
                f32x4 sv = {0.f, 0.f, 0.f, 0.f};
                sv = MFMA16x32(kf[mtk][0], qf[nt][0], sv, 0, 0, 0);
                sv = MFMA16x32(kf[mtk][1], qf[nt][1], sv, 0, 0, 0);
                const float p0 = __builtin_amdgcn_exp2f(sv[0]);
                const float p1 = __builtin_amdgcn_exp2f(sv[1]);
                const float p2 = __builtin_amdgcn_exp2f(sv[2]);
                const float p3 = __builtin_amdgcn_exp2f(sv[3]);
                uint2 pk;
                pk.x = pk_hu(p0, p1);
                pk.y = pk_hu(p2, p3);
                const int wp = (mtk * 4 + quad) ^ (l15 & 6);
                *(uint2*)(Pw + (nt * 16 + l15) * 32 + wp * 4) = pk;
            }
        }
        // prefetch next K tile (kf fully consumed)
        if (t < 31) {
            const u16* kt = Kb + (size_t)(t + 1) * 2048;
#pragma unroll
            for (int mtk = 0; mtk < 2; ++mtk)
#pragma unroll
                for (int kk = 0; kk < 2; ++kk)
                    kf_n[mtk][kk] = *(const short8*)(kt + (mtk * 16 + l15) * 64 + kk * 32 + quad * 8);
        }
        // ---- lp-MFMA + O += P.V ----
#pragma unroll
        for (int nt = 0; nt < 4; ++nt) {
            const int s16 = quad ^ ((l15 >> 1) & 3);
            const short8 pf = *(const short8*)(Pw + (nt * 16 + l15) * 32 + s16 * 8);
            lpa[nt] = MFMA16x32(pf, onesB, lpa[nt], 0, 0, 0);
#pragma unroll
            for (int ct = 0; ct < 4; ++ct)
                O[nt][ct] = MFMA16x32(pf, vf[ct], O[nt][ct], 0, 0, 0);
        }
        // prefetch next V tile; rotate
        if (t < 31) {
#pragma unroll
            for (int ct = 0; ct < 4; ++ct)
                vf_n[ct] = *(const short8*)(Vbp + (size_t)(t + 1) * 2048 + (ct * 16 + l15) * 32 + quad * 8);
#pragma unroll
            for (int mtk = 0; mtk < 2; ++mtk)
#pragma unroll
                for (int kk = 0; kk < 2; ++kk) kf[mtk][kk] = kf_n[mtk][kk];
#pragma unroll
            for (int ct = 0; ct < 4; ++ct) vf[ct] = vf_n[ct];
        }
    }

    __syncthreads();   // B1: all P traffic drained before epilogue overlays (R5 lesson)

    // lp partials: wave (h,s) -> 64 f32 at 52224 + (h*4+s)*256
    // (lpa D-layout: lanes duplicate across l15; rows nt*16 + quad*4 + r)
    if (l15 == 0) {
        float* lpw = (float*)(smem + 52224 + (h * 4 + s) * 256);
#pragma unroll
        for (int nt = 0; nt < 4; ++nt)
            *(f32x4*)(lpw + nt * 16 + quad * 4) = lpa[nt];
    }
    // O sections (bf16, stride 68) from s!=0 waves: section idx = h*3+s-1
    if (s != 0) {
        u16* sec = (u16*)smem + (h * 3 + s - 1) * 4352;
#pragma unroll
        for (int nt = 0; nt < 4; ++nt)
#pragma unroll
            for (int ct = 0; ct < 4; ++ct)
#pragma unroll
                for (int r = 0; r < 4; ++r)
                    sec[(nt * 16 + quad * 4 + r) * 68 + ct * 16 + l15] = f2bf(O[nt][ct][r]);
    }
    __syncthreads();   // B2

    float rinv[4][4];
    if (s == 0) {
#pragma unroll
        for (int nt = 0; nt < 4; ++nt)
#pragma unroll
            for (int r = 0; r < 4; ++r) {
                const int row = nt * 16 + quad * 4 + r;
                float sum = 0.f;
#pragma unroll
                for (int sx = 0; sx < 4; ++sx)
                    sum += ((const float*)(smem + 52224 + (h * 4 + sx) * 256))[row];
                rinv[nt][r] = 1.0f / sum;
            }
#pragma unroll
        for (int sx = 1; sx < 4; ++sx) {
            const u16* sec = (const u16*)smem + (h * 3 + sx - 1) * 4352;
#pragma unroll
            for (int nt = 0; nt < 4; ++nt)
#pragma unroll
                for (int ct = 0; ct < 4; ++ct)
#pragma unroll
                    for (int r = 0; r < 4; ++r)
                        O[nt][ct][r] += bf2f(sec[(nt * 16 + quad * 4 + r) * 68 + ct * 16 + l15]);
        }
    }
    // all waves: convert wm -> bf16 B-frags + bias (global f32, no LDS dependency)
    short8 wB[4][2];
    float bb[4];
#pragma unroll
    for (int nt = 0; nt < 4; ++nt) {
        const int d = nt * 16 + l15;
        const float* wr = wm + (size_t)d * 64 + quad * 8;
        const float4 a0 = *(const float4*)(wr);
        const float4 a1 = *(const float4*)(wr + 4);
        const float4 c0 = *(const float4*)(wr + 32);
        const float4 c1 = *(const float4*)(wr + 36);
        ((u32*)&wB[nt][0])[0] = (u32)f2bf(a0.x) | ((u32)f2bf(a0.y) << 16);
        ((u32*)&wB[nt][0])[1] = (u32)f2bf(a0.z) | ((u32)f2bf(a0.w) << 16);
        ((u32*)&wB[nt][0])[2] = (u32)f2bf(a1.x) | ((u32)f2bf(a1.y) << 16);
        ((u32*)&wB[nt][0])[3] = (u32)f2bf(a1.z) | ((u32)f2bf(a1.w) << 16);
        ((u32*)&wB[nt][1])[0] = (u32)f2bf(c0.x) | ((u32)f2bf(c0.y) << 16);
        ((u32*)&wB[nt][1])[1] = (u32)f2bf(c0.z) | ((u32)f2bf(c0.w) << 16);
        ((u32*)&wB[nt][1])[2] = (u32)f2bf(c1.x) | ((u32)f2bf(c1.y) << 16);
        ((u32*)&wB[nt][1])[3] = (u32)f2bf(c1.z) | ((u32)f2bf(c1.w) << 16);
        bb[nt] = bm[d];
    }
    __syncthreads();   // B3: section reads complete; M0 may overlay [0,16384)

    if (s == 0) {
        u16* M0 = (u16*)smem + h * 4096;     // 8 KB per h, swizzled 16B slots
#pragma unroll
        for (int nt = 0; nt < 4; ++nt)
#pragma unroll
            for (int ct = 0; ct < 4; ++ct)
#pragma unroll
                for (int r = 0; r < 4; ++r) {
                    const int lr = nt * 16 + quad * 4 + r;
                    const int ch = ct * 16 + l15;
                    const float v = O[nt][ct][r] * rinv[nt][r];
                    M0[lr * 64 + (((ch >> 3) ^ (lr & 7)) & 7) * 8 + (ch & 7)] = f2bf(v);
                }
    }
    __syncthreads();   // B4

    // mix: wave w handles rows [16w, 16w+16)
    const u16* M0r = (const u16*)smem + (wave >> 2) * 4096;
    const int lr = (wave & 3) * 16 + l15;
    const short8 af0 = *(const short8*)&M0r[lr * 64 + ((quad ^ (lr & 7)) & 7) * 8];
    const short8 af1 = *(const short8*)&M0r[lr * 64 + (((4 + quad) ^ (lr & 7)) & 7) * 8];
    float* Mf = (float*)(smem + 16384);      // [128][68] fp32, disjoint from M0
#pragma unroll
    for (int nt = 0; nt < 4; ++nt) {
        f32x4 acc = {0.f, 0.f, 0.f, 0.f};
        acc = MFMA16x32(af0, wB[nt][0], acc, 0, 0, 0);
        acc = MFMA16x32(af1, wB[nt][1], acc, 0, 0, 0);
#pragma unroll
        for (int r = 0; r < 4; ++r) {
            float v = acc[r] + bb[nt];
            v = v > 0.f ? v : 0.f;
            Mf[(wave * 16 + quad * 4 + r) * 68 + nt * 16 + l15] = v;
        }
    }
    __syncthreads();   // B5

    // 2x2 avg pool (== bilinear 2x downsample, half-pixel)
    const int ow = tid & 31;
    const int cb = (tid >> 5) & 15;
#pragma unroll
    for (int i = 0; i < 4; ++i) {
        const int c = cb + i * 16;
        const float v = 0.25f * (Mf[(2 * ow) * 68 + c] + Mf[(2 * ow + 1) * 68 + c]
                               + Mf[(64 + 2 * ow) * 68 + c] + Mf[(65 + 2 * ow) * 68 + c]);
        out[((size_t)(b * 64 + c) * 32 + oh) * 32 + ow] = v;
    }
}

extern "C" void kernel_launch(void* const* d_in, const int* in_sizes, int n_in,
                              void* d_out, int out_size, void* d_ws, size_t ws_size,
                              hipStream_t stream) {
    (void)in_sizes; (void)n_in; (void)out_size; (void)ws_size;
    const float* x  = (const float*)d_in[0];
    const float* wq = (const float*)d_in[1];
    const float* bq = (const float*)d_in[2];
    const float* wk = (const float*)d_in[3];
    const float* bk = (const float*)d_in[4];
    const float* wv = (const float*)d_in[5];
    const float* bv = (const float*)d_in[6];
    const float* wm = (const float*)d_in[7];
    const float* bm = (const float*)d_in[8];

    // ws: Q bf16 [8][4096][64] | K bf16 [8][4096][64] | Vp bf16 [8][128][64][32] = 12 MB
    u16* Q  = (u16*)d_ws;
    u16* K  = Q + (size_t)8 * NTOK * 64;
    u16* Vp = K + (size_t)8 * NTOK * 64;

    qkv_mfma4<<<512, 256, 0, stream>>>(x, wq, bq, wk, bk, wv, bv, Q, K, Vp);
    attn6<<<256, 512, 0, stream>>>(Q, K, Vp, wm, bm, (float*)d_out);
}

// Round 8
// 135.681 us; speedup vs baseline: 1.5521x; 1.0076x over previous
//
#include <hip/hip_runtime.h>
#include <stdint.h>

typedef unsigned short u16;
typedef unsigned int   u32;
typedef __attribute__((ext_vector_type(8)))  short short8;
typedef __attribute__((ext_vector_type(4)))  float f32x4;
typedef __attribute__((ext_vector_type(16))) float f32x16;

#define NTOK 4096
#define LOG2E 1.44269504088896340736f
#define QS    (0.125f * LOG2E)

// round-to-nearest-even f32 -> bf16
__device__ __forceinline__ u16 f2bf(float f) {
    u32 u = __builtin_bit_cast(u32, f);
    u += 0x7fffu + ((u >> 16) & 1u);
    return (u16)(u >> 16);
}
__device__ __forceinline__ float bf2f(u16 v) {
    return __builtin_bit_cast(float, (u32)v << 16);
}
// pack two positive floats to bf16 pair (round-half-up), low half = a. 3 VALU ops.
__device__ __forceinline__ u32 pk_hu(float a, float b) {
    u32 ua = __builtin_bit_cast(u32, a) + 0x8000u;
    u32 ub = __builtin_bit_cast(u32, b) + 0x8000u;
    return __builtin_amdgcn_perm(ub, ua, 0x07060302);  // {ub.hi16, ua.hi16}
}
__device__ __forceinline__ f32x16 zero16() {
    f32x16 v;
#pragma unroll
    for (int i = 0; i < 16; ++i) v[i] = 0.f;
    return v;
}

#define MFMA16x32 __builtin_amdgcn_mfma_f32_16x16x32_bf16
#define MFMA32x16 __builtin_amdgcn_mfma_f32_32x32x16_bf16

// ---------------- kernel 1: QKV projection via MFMA (frozen from R7) ----------------
__global__ __launch_bounds__(256) void qkv_mfma4(
    const float* __restrict__ x,
    const float* __restrict__ wq, const float* __restrict__ bq,
    const float* __restrict__ wk, const float* __restrict__ bk,
    const float* __restrict__ wv, const float* __restrict__ bv,
    u16* __restrict__ Q, u16* __restrict__ K, u16* __restrict__ Vp)
{
    __shared__ __align__(16) u16 Wl[3 * 64 * 72];
    __shared__ __align__(16) u16 Xl[64 * 64];
    const int tid  = threadIdx.x;
    const int b    = blockIdx.x & 7;
    const int slab = blockIdx.x >> 3;
    const int n0   = slab << 6;
    const int wave = tid >> 6;
    const int lane = tid & 63;
    const int quad = lane >> 4;
    const int l15  = lane & 15;

#pragma unroll
    for (int j = 0; j < 12; ++j) {
        const float* src = (j < 4) ? wq : (j < 8) ? wk : wv;
        const float sc = (j < 4) ? QS : 1.0f;
        const int idx = (j & 3) * 1024 + tid * 4;
        const float4 v = *(const float4*)(src + idx);
        uint2 pk;
        pk.x = (u32)f2bf(v.x * sc) | ((u32)f2bf(v.y * sc) << 16);
        pk.y = (u32)f2bf(v.z * sc) | ((u32)f2bf(v.w * sc) << 16);
        *(uint2*)&Wl[(j >> 2) * 4608 + (idx >> 6) * 72 + (idx & 63)] = pk;
    }

    float4 xs[4];
#pragma unroll
    for (int g = 0; g < 4; ++g) {
        const int ch = g * 16 + wave * 4 + quad;
        xs[g] = *(const float4*)(x + ((size_t)(b * 64 + ch)) * NTOK + n0 + l15 * 4);
    }
#pragma unroll
    for (int g = 0; g < 4; ++g) {
        const int ch = g * 16 + wave * 4 + quad;
        const float vv[4] = {xs[g].x, xs[g].y, xs[g].z, xs[g].w};
#pragma unroll
        for (int e = 0; e < 4; ++e) {
            const int tok = l15 * 4 + e;
            Xl[tok * 64 + (((ch >> 3) ^ (tok & 7)) & 7) * 8 + (ch & 7)] = f2bf(vv[e]);
        }
    }
    __syncthreads();

    const int row0 = wave * 16 + l15;
    short8 xf[2];
#pragma unroll
    for (int kk = 0; kk < 2; ++kk)
        xf[kk] = *(const short8*)&Xl[row0 * 64 + (((kk * 4 + quad) ^ (row0 & 7)) & 7) * 8];

    const size_t tokbase = (size_t)b * NTOK + n0 + wave * 16;

#pragma unroll
    for (int mat = 0; mat < 2; ++mat) {
        const float* bias = (mat == 0) ? bq : bk;
        const float bsc = (mat == 0) ? QS : 1.0f;
#pragma unroll
        for (int mt = 0; mt < 4; ++mt) {
            const u16* wr = &Wl[mat * 4608 + (mt * 16 + l15) * 72 + quad * 8];
            const short8 wf0 = *(const short8*)(wr);
            const short8 wf1 = *(const short8*)(wr + 32);
            f32x4 acc = {0.f, 0.f, 0.f, 0.f};
            acc = MFMA16x32(wf0, xf[0], acc, 0, 0, 0);
            acc = MFMA16x32(wf1, xf[1], acc, 0, 0, 0);
            const float4 b4 = *(const float4*)(bias + mt * 16 + quad * 4);
            uint2 pk;
            pk.x = (u32)f2bf(acc[0] + b4.x * bsc) | ((u32)f2bf(acc[1] + b4.y * bsc) << 16);
            pk.y = (u32)f2bf(acc[2] + b4.z * bsc) | ((u32)f2bf(acc[3] + b4.w * bsc) << 16);
            u16* dst = (mat == 0) ? Q : K;
            *(uint2*)(dst + (tokbase + l15) * 64 + mt * 16 + quad * 4) = pk;
        }
    }

    __syncthreads();
    u16* Vl = Xl;
    const int tok = wave * 16 + l15;
#pragma unroll
    for (int mt = 0; mt < 4; ++mt) {
        const u16* wr = &Wl[2 * 4608 + (mt * 16 + l15) * 72 + quad * 8];
        const short8 wf0 = *(const short8*)(wr);
        const short8 wf1 = *(const short8*)(wr + 32);
        f32x4 acc = {0.f, 0.f, 0.f, 0.f};
        acc = MFMA16x32(wf0, xf[0], acc, 0, 0, 0);
        acc = MFMA16x32(wf1, xf[1], acc, 0, 0, 0);
        const float4 b4 = *(const float4*)(bv + mt * 16 + quad * 4);
        const float o[4] = {acc[0] + b4.x, acc[1] + b4.y, acc[2] + b4.z, acc[3] + b4.w};
#pragma unroll
        for (int r = 0; r < 4; ++r) {
            const int d = mt * 16 + quad * 4 + r;
            Vl[d * 64 + (((tok >> 3) ^ ((d >> 1) & 7)) & 7) * 8 + (tok & 7)] = f2bf(o[r]);
        }
    }
    __syncthreads();

#pragma unroll
    for (int dd = 0; dd < 4; ++dd) {
        const int d2   = (tid >> 4) + dd * 16;
        const int tok0 = (tid & 15) * 4;
        const int slot = ((tok0 >> 3) ^ ((d2 >> 1) & 7)) & 7;
        const uint2 v2 = *(const uint2*)&Vl[d2 * 64 + slot * 8 + (tok0 & 7)];
        const int gt = slab * 2 + (tok0 >> 5);
        *(uint2*)(Vp + (((size_t)b * 128 + gt) * 64 + d2) * 32 + (tok0 & 31)) = v2;
    }
}

// ---------------- kernel 2: fused attention + mix + 2x2 pool ----------------
// grid 256 = oh(32) x b(8 low). Block 512 = 8 waves = 2 Q-halves (h) x 4 KV
// slices (s). 32x32x16 MFMAs. K-loop is LDS-FREE: S^T = K.Q^T D-layout
// (col=lane&31=qrow, row=(r&3)+8(r>>2)+4*(lane>>5)=token, m74) converts to the
// PV B-operand layout (k=8*(lane>>5)+j, n=lane&31) with 4 shfl_xor(32) +
// cndmask selects per n-tile -- no P round-trip, no barriers, no conflicts.
// lp = per-lane adds (fixed qrow per lane) + one end shfl. Epilogue = R7's
// section exchange (bf16 partials, one barrier), mix MFMA, 2x2 pool.
__global__ __launch_bounds__(512, 2) void attn7(
    const u16* __restrict__ Q, const u16* __restrict__ K,
    const u16* __restrict__ Vp,
    const float* __restrict__ wm, const float* __restrict__ bm,
    float* __restrict__ out)
{
    __shared__ __align__(16) char smem[54272];
    const int tid  = threadIdx.x;
    const int wave = tid >> 6;
    const int lane = tid & 63;
    const int c31  = lane & 31;
    const int hw   = lane >> 5;          // half-wave
    const int quad = lane >> 4;
    const int l15  = lane & 15;
    const int h    = wave >> 2;          // Q half (64 rows)
    const int s    = wave & 3;           // KV slice (1024 tokens)
    const int b    = blockIdx.x & 7;
    const int oh   = blockIdx.x >> 3;
    const int n0   = oh * 128;

    // Q B-frags: B[k=ch][n=qrow]: lane (c31,hw) reads Q[qrow=nt*32+c31][ks*16+hw*8+j]
    short8 qf[2][4];
#pragma unroll
    for (int nt = 0; nt < 2; ++nt)
#pragma unroll
        for (int ks = 0; ks < 4; ++ks)
            qf[nt][ks] = *(const short8*)(Q + ((size_t)(b * NTOK + n0 + h * 64 + nt * 32 + c31)) * 64
                                            + ks * 16 + hw * 8);

    const u16* Kb  = K + ((size_t)b * NTOK + s * 1024) * 64;
    const u16* Vbp = Vp + ((size_t)b * 128 + s * 32) * 2048;

    f32x16 O[2][2];                       // [mt][nt] = O^T tiles, 64 AGPR
#pragma unroll
    for (int mt = 0; mt < 2; ++mt)
#pragma unroll
        for (int nt = 0; nt < 2; ++nt) O[mt][nt] = zero16();
    float lpa[2] = {0.f, 0.f};

    auto load_kv = [&](short8 (&kf)[4], short8 (&vf)[4], int t) {
        const int tc = (t < 32) ? t : 31;          // clamp: last prefetch stays in-bounds
        const u16* kt = Kb + (size_t)tc * 2048;
#pragma unroll
        for (int ks = 0; ks < 4; ++ks)
            kf[ks] = *(const short8*)(kt + c31 * 64 + ks * 16 + hw * 8);
        const u16* vt = Vbp + (size_t)tc * 2048;
#pragma unroll
        for (int mk = 0; mk < 4; ++mk)
            vf[mk] = *(const short8*)(vt + ((mk >> 1) * 32 + c31) * 32 + (mk & 1) * 16 + hw * 8);
    };

    auto tile_tail = [&](const f32x16 (&sv)[2], const short8 (&vf)[4]) {
#pragma unroll
        for (int nt = 0; nt < 2; ++nt) {
            float p[16];
#pragma unroll
            for (int r = 0; r < 16; ++r) p[r] = __builtin_amdgcn_exp2f(sv[nt][r]);
            lpa[nt] += (((p[0] + p[1]) + (p[2] + p[3])) + ((p[4] + p[5]) + (p[6] + p[7])))
                     + (((p[8] + p[9]) + (p[10] + p[11])) + ((p[12] + p[13]) + (p[14] + p[15])));
            u32 g[8];
#pragma unroll
            for (int gi = 0; gi < 8; ++gi) g[gi] = pk_hu(p[2 * gi], p[2 * gi + 1]);
            // cross-half exchange: hw0 supplies g2,g3,g6,g7; hw1 supplies g0,g1,g4,g5
            const u32 rA = __shfl_xor(hw ? g[0] : g[2], 32);
            const u32 rB = __shfl_xor(hw ? g[1] : g[3], 32);
            const u32 rC = __shfl_xor(hw ? g[4] : g[6], 32);
            const u32 rD = __shfl_xor(hw ? g[5] : g[7], 32);
            uint4 B0, B1;                 // P^T B-frags, k-windows 0-15 / 16-31
            B0.x = hw ? rA : g[0];  B0.y = hw ? rB : g[1];
            B0.z = hw ? g[2] : rA;  B0.w = hw ? g[3] : rB;
            B1.x = hw ? rC : g[4];  B1.y = hw ? rD : g[5];
            B1.z = hw ? g[6] : rC;  B1.w = hw ? g[7] : rD;
            const short8 pb0 = __builtin_bit_cast(short8, B0);
            const short8 pb1 = __builtin_bit_cast(short8, B1);
            O[0][nt] = MFMA32x16(vf[0], pb0, O[0][nt], 0, 0, 0);
            O[0][nt] = MFMA32x16(vf[1], pb1, O[0][nt], 0, 0, 0);
            O[1][nt] = MFMA32x16(vf[2], pb0, O[1][nt], 0, 0, 0);
            O[1][nt] = MFMA32x16(vf[3], pb1, O[1][nt], 0, 0, 0);
        }
    };

    short8 kfA[4], vfA[4], kfB[4], vfB[4];
    load_kv(kfA, vfA, 0);

#pragma unroll 1
    for (int tt = 0; tt < 16; ++tt) {
        const int t0 = tt * 2;
        f32x16 sv0[2];
#pragma unroll
        for (int nt = 0; nt < 2; ++nt) {
            f32x16 a = zero16();
            a = MFMA32x16(kfA[0], qf[nt][0], a, 0, 0, 0);
            a = MFMA32x16(kfA[1], qf[nt][1], a, 0, 0, 0);
            a = MFMA32x16(kfA[2], qf[nt][2], a, 0, 0, 0);
            a = MFMA32x16(kfA[3], qf[nt][3], a, 0, 0, 0);
            sv0[nt] = a;
        }
        load_kv(kfB, vfB, t0 + 1);        // prefetch overlaps exp2/shfl/PV
        tile_tail(sv0, vfA);

        f32x16 sv1[2];
#pragma unroll
        for (int nt = 0; nt < 2; ++nt) {
            f32x16 a = zero16();
            a = MFMA32x16(kfB[0], qf[nt][0], a, 0, 0, 0);
            a = MFMA32x16(kfB[1], qf[nt][1], a, 0, 0, 0);
            a = MFMA32x16(kfB[2], qf[nt][2], a, 0, 0, 0);
            a = MFMA32x16(kfB[3], qf[nt][3], a, 0, 0, 0);
            sv1[nt] = a;
        }
        load_kv(kfA, vfA, t0 + 2);        // clamped at end (values unused)
        tile_tail(sv1, vfB);
    }

    // ---- epilogue ----
    // combine lp halves (disjoint token sets), lane (c31,*) -> lp[qrow nt*32+c31]
#pragma unroll
    for (int nt = 0; nt < 2; ++nt) lpa[nt] += __shfl_xor(lpa[nt], 32);

    float* lpbuf = (float*)(smem + 52224);
    if (hw == 0) {
#pragma unroll
        for (int nt = 0; nt < 2; ++nt)
            lpbuf[(h * 4 + s) * 64 + nt * 32 + c31] = lpa[nt];
    }
    if (s != 0) {                          // bf16 O-partial sections
        u16* sec = (u16*)smem + (h * 3 + s - 1) * 4352;
#pragma unroll
        for (int mt = 0; mt < 2; ++mt)
#pragma unroll
            for (int nt = 0; nt < 2; ++nt)
#pragma unroll
                for (int r = 0; r < 16; ++r) {
                    const int ch = mt * 32 + (r & 3) + 8 * (r >> 2) + 4 * hw;
                    sec[(nt * 32 + c31) * 68 + ch] = f2bf(O[mt][nt][r]);
                }
    }
    __syncthreads();   // B2: all partials visible

    float rinv[2];
    if (s == 0) {
#pragma unroll
        for (int nt = 0; nt < 2; ++nt) {
            float sum = 0.f;
#pragma unroll
            for (int sx = 0; sx < 4; ++sx)
                sum += lpbuf[(h * 4 + sx) * 64 + nt * 32 + c31];
            rinv[nt] = 1.0f / sum;
        }
#pragma unroll
        for (int sx = 1; sx < 4; ++sx) {
            const u16* sec = (const u16*)smem + (h * 3 + sx - 1) * 4352;
#pragma unroll
            for (int mt = 0; mt < 2; ++mt)
#pragma unroll
                for (int nt = 0; nt < 2; ++nt)
#pragma unroll
                    for (int r = 0; r < 16; ++r) {
                        const int ch = mt * 32 + (r & 3) + 8 * (r >> 2) + 4 * hw;
                        O[mt][nt][r] += bf2f(sec[(nt * 32 + c31) * 68 + ch]);
                    }
        }
    }
    // all waves: convert wm -> bf16 B-frags + bias (global reads, overlaps reduction)
    short8 wB[4][2];
    float bb[4];
#pragma unroll
    for (int nt = 0; nt < 4; ++nt) {
        const int d = nt * 16 + l15;
        const float* wr = wm + (size_t)d * 64 + quad * 8;
        const float4 a0 = *(const float4*)(wr);
        const float4 a1 = *(const float4*)(wr + 4);
        const float4 c0 = *(const float4*)(wr + 32);
        const float4 c1 = *(const float4*)(wr + 36);
        ((u32*)&wB[nt][0])[0] = pk_hu(a0.y, a0.x) ^ 0u, ((u32*)&wB[nt][0])[0] = (u32)f2bf(a0.x) | ((u32)f2bf(a0.y) << 16);
        ((u32*)&wB[nt][0])[1] = (u32)f2bf(a0.z) | ((u32)f2bf(a0.w) << 16);
        ((u32*)&wB[nt][0])[2] = (u32)f2bf(a1.x) | ((u32)f2bf(a1.y) << 16);
        ((u32*)&wB[nt][0])[3] = (u32)f2bf(a1.z) | ((u32)f2bf(a1.w) << 16);
        ((u32*)&wB[nt][1])[0] = (u32)f2bf(c0.x) | ((u32)f2bf(c0.y) << 16);
        ((u32*)&wB[nt][1])[1] = (u32)f2bf(c0.z) | ((u32)f2bf(c0.w) << 16);
        ((u32*)&wB[nt][1])[2] = (u32)f2bf(c1.x) | ((u32)f2bf(c1.y) << 16);
        ((u32*)&wB[nt][1])[3] = (u32)f2bf(c1.z) | ((u32)f2bf(c1.w) << 16);
        bb[nt] = bm[d];
    }
    __syncthreads();   // B3: section reads done; M0 may overlay

    if (s == 0) {      // normalize -> M0 bf16 (swizzled [qrow][ch]) at h*8KB
        u16* M0 = (u16*)smem + h * 4096;
#pragma unroll
        for (int mt = 0; mt < 2; ++mt)
#pragma unroll
            for (int nt = 0; nt < 2; ++nt)
#pragma unroll
                for (int r = 0; r < 16; ++r) {
                    const int lr = nt * 32 + c31;
                    const int ch = mt * 32 + (r & 3) + 8 * (r >> 2) + 4 * hw;
                    const float v = O[mt][nt][r] * rinv[nt];
                    M0[lr * 64 + (((ch >> 3) ^ (lr & 7)) & 7) * 8 + (ch & 7)] = f2bf(v);
                }
    }
    __syncthreads();   // B4

    // mix: wave w handles rows [16w, 16w+16) (R7-proven)
    const u16* M0r = (const u16*)smem + (wave >> 2) * 4096;
    const int lr = (wave & 3) * 16 + l15;
    const short8 af0 = *(const short8*)&M0r[lr * 64 + ((quad ^ (lr & 7)) & 7) * 8];
    const short8 af1 = *(const short8*)&M0r[lr * 64 + (((4 + quad) ^ (lr & 7)) & 7) * 8];
    float* Mf = (float*)(smem + 16384);      // [128][68] fp32, disjoint from M0
#pragma unroll
    for (int nt = 0; nt < 4; ++nt) {
        f32x4 acc = {0.f, 0.f, 0.f, 0.f};
        acc = MFMA16x32(af0, wB[nt][0], acc, 0, 0, 0);
        acc = MFMA16x32(af1, wB[nt][1], acc, 0, 0, 0);
#pragma unroll
        for (int r = 0; r < 4; ++r) {
            float v = acc[r] + bb[nt];
            v = v > 0.f ? v : 0.f;
            Mf[(wave * 16 + quad * 4 + r) * 68 + nt * 16 + l15] = v;
        }
    }
    __syncthreads();   // B5

    // 2x2 avg pool (== bilinear 2x downsample, half-pixel)
    const int ow = tid & 31;
    const int cb = (tid >> 5) & 15;
#pragma unroll
    for (int i = 0; i < 4; ++i) {
        const int c = cb + i * 16;
        const float v = 0.25f * (Mf[(2 * ow) * 68 + c] + Mf[(2 * ow + 1) * 68 + c]
                               + Mf[(64 + 2 * ow) * 68 + c] + Mf[(65 + 2 * ow) * 68 + c]);
        out[((size_t)(b * 64 + c) * 32 + oh) * 32 + ow] = v;
    }
}

extern "C" void kernel_launch(void* const* d_in, const int* in_sizes, int n_in,
                              void* d_out, int out_size, void* d_ws, size_t ws_size,
                              hipStream_t stream) {
    (void)in_sizes; (void)n_in; (void)out_size; (void)ws_size;
    const float* x  = (const float*)d_in[0];
    const float* wq = (const float*)d_in[1];
    const float* bq = (const float*)d_in[2];
    const float* wk = (const float*)d_in[3];
    const float* bk = (const float*)d_in[4];
    const float* wv = (const float*)d_in[5];
    const float* bv = (const float*)d_in[6];
    const float* wm = (const float*)d_in[7];
    const float* bm = (const float*)d_in[8];

    // ws: Q bf16 [8][4096][64] | K bf16 [8][4096][64] | Vp bf16 [8][128][64][32] = 12 MB
    u16* Q  = (u16*)d_ws;
    u16* K  = Q + (size_t)8 * NTOK * 64;
    u16* Vp = K + (size_t)8 * NTOK * 64;

    qkv_mfma4<<<512, 256, 0, stream>>>(x, wq, bq, wk, bk, wv, bv, Q, K, Vp);
    attn7<<<256, 512, 0, stream>>>(Q, K, Vp, wm, bm, (float*)d_out);
}